// Round 5
// baseline (428.394 us; speedup 1.0000x reference)
//
#include <hip/hip_runtime.h>

#define B_SZ 4096
#define S_SZ 128
#define XD 5
#define EH 128
#define DH 256
#define DSTEPS 10

typedef short v8s __attribute__((ext_vector_type(8)));
typedef float v4f __attribute__((ext_vector_type(4)));
typedef float v16f __attribute__((ext_vector_type(16)));

__device__ __forceinline__ float bf2f(unsigned short u) {
    union { unsigned int i; float f; } v; v.i = ((unsigned int)u) << 16; return v.f;
}
__device__ __forceinline__ unsigned short f2bf(float f) {
    union { float f; unsigned int i; } v; v.f = f;
    unsigned int x = v.i;
    return (unsigned short)((x + 0x7FFFu + ((x >> 16) & 1u)) >> 16);
}
__device__ __forceinline__ float fexp2(float x) { return __builtin_amdgcn_exp2f(x); }
__device__ __forceinline__ float frcp(float x) { return __builtin_amdgcn_rcpf(x); }
__device__ __forceinline__ float sigmoidf_(float x) {
    return frcp(1.f + fexp2(-1.44269504088896f * x));
}
__device__ __forceinline__ float tanhf_(float x) {
    float e = fexp2(2.88539008177793f * x);   // e^(2x)
    return 1.f - 2.f * frcp(e + 1.f);
}

// ---------------------------------------------------------------- prep
// Converts fp32 weights -> bf16 workspace copies, pads out[:,10:,:] = 1.
__global__ void prep_kernel(const float* __restrict__ dWih,   // [768][129]
                            const float* __restrict__ eWhh,   // [384][128]
                            const float* __restrict__ eWih,   // [384][5]
                            const float* __restrict__ dWhh,   // [768][256]
                            unsigned short* __restrict__ wihp,     // [768][136] bf16
                            unsigned short* __restrict__ eWhh_bf,  // [384][128] bf16
                            unsigned short* __restrict__ eWih_bf,  // [384][5]  bf16
                            unsigned short* __restrict__ dWhh_bf,  // [768][256] bf16
                            float* __restrict__ out)               // [B][S][4] fp32
{
    const int NW  = 768 * 136;      // wihp
    const int NE1 = 384 * 128;      // eWhh
    const int NE2 = 384 * 5;        // eWih
    const int ND  = 768 * 256;      // dWhh
    const int NO  = B_SZ * S_SZ * 4;
    const int total = NW + NE1 + NE2 + ND + NO;
    for (int i = blockIdx.x * 256 + threadIdx.x; i < total; i += gridDim.x * 256) {
        int idx = i;
        if (idx < NW) {
            int col = idx / 136, k = idx - col * 136;
            wihp[idx] = (k < 129) ? f2bf(dWih[col * 129 + k]) : (unsigned short)0;
            continue;
        }
        idx -= NW;
        if (idx < NE1) { eWhh_bf[idx] = f2bf(eWhh[idx]); continue; }
        idx -= NE1;
        if (idx < NE2) { eWih_bf[idx] = f2bf(eWih[idx]); continue; }
        idx -= NE2;
        if (idx < ND)  { dWhh_bf[idx] = f2bf(dWhh[idx]); continue; }
        idx -= ND;
        int s = (idx >> 2) & (S_SZ - 1);
        if (s >= DSTEPS) out[idx] = 1.0f;
    }
}

// ---------------------------------------------------------------- encoder
// (r2 version — fastest measured; fragment-residency pins proved neutral.)
__global__ __launch_bounds__(512) void enc_kernel(
    const float* __restrict__ x,              // [B][S][5] fp32
    const unsigned short* __restrict__ Wih,   // [384][5]  bf16
    const unsigned short* __restrict__ Whh,   // [384][128] bf16
    const float* __restrict__ bih,            // [384] fp32
    const float* __restrict__ bhh,            // [384] fp32
    unsigned short* __restrict__ ctex)        // [B][128] bf16
{
    __shared__ unsigned short xs[S_SZ][16][8];     // 32 KB
    __shared__ unsigned short hb[2][16][136];      // 8.5 KB, +8 pad
    __shared__ unsigned short zpad[8];

    const int tid = threadIdx.x;
    const int wv = tid >> 6;
    const int lane = tid & 63;
    const int n = lane & 15;
    const int kg = lane >> 4;       // K-group / C-row quad
    const int r0 = blockIdx.x * 16;

    for (int i = tid; i < 2 * 16 * 136; i += 512) ((unsigned short*)hb)[i] = 0;
    if (tid < 8) zpad[tid] = 0;
    for (int i = tid; i < 16 * S_SZ * 8; i += 512) {
        int m = i >> 10;            // / (128*8)
        int rem = i & 1023;
        int t = rem >> 3;
        int j = rem & 7;
        unsigned short v = 0;
        if (j < XD) v = f2bf(x[(size_t)(r0 + m) * (S_SZ * XD) + t * XD + j]);
        xs[t][m][j] = v;
    }

    const int colw = wv * 16 + n;   // this lane's column within H
    v8s fw[3][4];                   // Whh B-frags [gate][K-tile]
    v8s fx[3];                      // Wih B-frags [gate]
    #pragma unroll
    for (int g = 0; g < 3; ++g) {
        int gcol = g * EH + colw;
        #pragma unroll
        for (int kt = 0; kt < 4; ++kt)
            fw[g][kt] = *(const v8s*)&Whh[gcol * EH + kt * 32 + kg * 8];
        v8s t = {0, 0, 0, 0, 0, 0, 0, 0};
        if (kg == 0) {
            const unsigned short* p = &Wih[gcol * XD];
            #pragma unroll
            for (int j = 0; j < XD; ++j) t[j] = (short)p[j];
        }
        fx[g] = t;
    }
    const float b_r  = bih[colw]          + bhh[colw];
    const float b_z  = bih[EH + colw]     + bhh[EH + colw];
    const float bi_n = bih[2 * EH + colw];
    const float bh_n = bhh[2 * EH + colw];

    float hst[4] = {0.f, 0.f, 0.f, 0.f};
    __syncthreads();

    #pragma unroll 2
    for (int t = 0; t < S_SZ; ++t) {
        const int p = t & 1;
        v8s a[4];
        #pragma unroll
        for (int kt = 0; kt < 4; ++kt)
            a[kt] = *(const v8s*)&hb[p][n][kt * 32 + kg * 8];
        const unsigned short* xsrc = (kg == 0) ? &xs[t][n][0] : &zpad[0];
        v8s ax = *(const v8s*)xsrc;

        v4f accr  = {b_r, b_r, b_r, b_r};
        v4f accz  = {b_z, b_z, b_z, b_z};
        v4f acchn = {bh_n, bh_n, bh_n, bh_n};
        v4f accin = {bi_n, bi_n, bi_n, bi_n};
        #pragma unroll
        for (int kt = 0; kt < 4; ++kt) {
            accr  = __builtin_amdgcn_mfma_f32_16x16x32_bf16(a[kt], fw[0][kt], accr, 0, 0, 0);
            accz  = __builtin_amdgcn_mfma_f32_16x16x32_bf16(a[kt], fw[1][kt], accz, 0, 0, 0);
            acchn = __builtin_amdgcn_mfma_f32_16x16x32_bf16(a[kt], fw[2][kt], acchn, 0, 0, 0);
        }
        accr  = __builtin_amdgcn_mfma_f32_16x16x32_bf16(ax, fx[0], accr, 0, 0, 0);
        accz  = __builtin_amdgcn_mfma_f32_16x16x32_bf16(ax, fx[1], accz, 0, 0, 0);
        accin = __builtin_amdgcn_mfma_f32_16x16x32_bf16(ax, fx[2], accin, 0, 0, 0);

        #pragma unroll
        for (int e = 0; e < 4; ++e) {
            float r = sigmoidf_(accr[e]);
            float z = sigmoidf_(accz[e]);
            float nn = tanhf_(accin[e] + r * acchn[e]);
            float h = (1.f - z) * nn + z * hst[e];
            hst[e] = h;
            hb[1 - p][kg * 4 + e][colw] = f2bf(h);
        }
        __syncthreads();
    }
    #pragma unroll
    for (int e = 0; e < 4; ++e)
        ctex[(size_t)(r0 + kg * 4 + e) * EH + colw] = f2bf(hst[e]);
}

// ---------------------------------------------------------------- gi_base
// gib[b][768] = contex @ dec_Wih[:, :128].T + dec_bih   (bf16 out)
__global__ __launch_bounds__(256, 1) void gib_kernel(
    const unsigned short* __restrict__ ctex,   // [B][128] bf16
    const unsigned short* __restrict__ wihp,   // [768][136] bf16
    const float* __restrict__ dbih,            // [768] fp32
    unsigned short* __restrict__ gib)          // [B][768] bf16
{
    const int tid = threadIdx.x;
    const int wv = tid >> 6, lane = tid & 63, n = lane & 15, kg = lane >> 4;
    const int rb = blockIdx.x * 64 + wv * 16;
    const int cb = blockIdx.y * 64;

    v8s a[4];
    #pragma unroll
    for (int kt = 0; kt < 4; ++kt)
        a[kt] = *(const v8s*)&ctex[(size_t)(rb + n) * EH + kt * 32 + kg * 8];

    #pragma unroll
    for (int nt = 0; nt < 4; ++nt) {
        int col = cb + nt * 16 + n;
        float bb = dbih[col];
        v4f acc = {bb, bb, bb, bb};
        #pragma unroll
        for (int kt = 0; kt < 4; ++kt) {
            v8s b = *(const v8s*)&wihp[col * 136 + kt * 32 + kg * 8];
            acc = __builtin_amdgcn_mfma_f32_16x16x32_bf16(a[kt], b, acc, 0, 0, 0);
        }
        #pragma unroll
        for (int e = 0; e < 4; ++e)
            gib[(size_t)(rb + kg * 4 + e) * 768 + col] = f2bf(acc[e]);
    }
}

// ---------------------------------------------------------------- fused decoder
// ONE kernel for all 10 steps + output projection. 128 blocks x 512 thr;
// block owns 32 batch rows and ALL 256 h-cols -> no cross-block deps.
// h state: LDS (A-frags) + per-lane regs (C-layout, for the z*h_old term).
// Whh streamed from L2 directly into B-frags every step (384KB, L2-resident).
// MFMA: 32x32x16 bf16. Wave w owns h-cols [32w,32w+32) => its r/z/n gate
// cols are {hc, 256+hc, 512+hc}: gate math is fully in-lane.
__global__ __launch_bounds__(512)
__attribute__((amdgpu_waves_per_eu(2, 2)))
void dec_fused_kernel(
    const unsigned short* __restrict__ dWhh,  // [768][256] bf16
    const float* __restrict__ dWih,           // [768][129] fp32 (col 128 = y wt)
    const float* __restrict__ dbhh,           // [768] fp32
    const float* __restrict__ y,              // [B][128] fp32
    const unsigned short* __restrict__ gib,   // [B][768] bf16 (incl dbih)
    const float* __restrict__ linW,           // [4][256] fp32
    const float* __restrict__ linb,           // [4] fp32
    float* __restrict__ out)                  // [B][S][4] fp32
{
    // stride 264: 528B rows -> 16B-aligned b128; (132 dw % 32) = 4 -> worst
    // 4-way bank aliasing on A-reads (1.58x on a minor term; W-stream is the wall)
    __shared__ unsigned short hsh[32][264];   // 16.5 KB  h state (bf16)
    __shared__ float lwsh[4][256];            // 4 KB     lin_W
    __shared__ float psum[32][4][4];          // 2 KB     out partials

    const int tid  = threadIdx.x;
    const int w    = tid >> 6;       // wave id = h-col tile
    const int lane = tid & 63;
    const int n    = lane & 31;      // A-row (batch) AND B-col (gate col in tile)
    const int kh   = lane >> 5;      // K-half
    const int rb   = blockIdx.x * 32;
    const int hcol = w * 32 + n;

    for (int i = tid; i < 32 * 264; i += 512) ((unsigned short*)hsh)[i] = 0x3F80; // h0=1
    for (int i = tid; i < 4 * 256; i += 512) ((float*)lwsh)[i] = linW[i];

    // per-lane constants (C/D rows: (e&3) + 8*(e>>2) + 4*kh)
    float bias_g[3], wy_g[3];
    #pragma unroll
    for (int g = 0; g < 3; ++g) {
        bias_g[g] = dbhh[g * DH + hcol];
        wy_g[g]   = dWih[(size_t)(g * DH + hcol) * 129 + 128];
    }
    float gv[3][16];   // gib is constant across steps -> preload once
    #pragma unroll
    for (int g = 0; g < 3; ++g)
        #pragma unroll
        for (int e = 0; e < 16; ++e) {
            int row = (e & 3) + 8 * (e >> 2) + 4 * kh;
            gv[g][e] = bf2f(gib[(size_t)(rb + row) * 768 + g * DH + hcol]);
        }

    float hprev[16];
    #pragma unroll
    for (int e = 0; e < 16; ++e) hprev[e] = 1.0f;

    const unsigned short* wr = &dWhh[(size_t)(0 * DH + hcol) * DH + kh * 8];
    const unsigned short* wz = &dWhh[(size_t)(1 * DH + hcol) * DH + kh * 8];
    const unsigned short* wn = &dWhh[(size_t)(2 * DH + hcol) * DH + kh * 8];

    __syncthreads();

    for (int t = 0; t < DSTEPS; ++t) {
        v16f accr, accz, accn;
        #pragma unroll
        for (int e = 0; e < 16; ++e) {
            accr[e] = bias_g[0]; accz[e] = bias_g[1]; accn[e] = bias_g[2];
        }

        #pragma unroll
        for (int kt = 0; kt < 16; ++kt) {
            v8s a  = *(const v8s*)&hsh[n][kt * 16 + kh * 8];
            v8s br = *(const v8s*)&wr[kt * 16];
            v8s bz = *(const v8s*)&wz[kt * 16];
            v8s bn = *(const v8s*)&wn[kt * 16];
            accr = __builtin_amdgcn_mfma_f32_32x32x16_bf16(a, br, accr, 0, 0, 0);
            accz = __builtin_amdgcn_mfma_f32_32x32x16_bf16(a, bz, accz, 0, 0, 0);
            accn = __builtin_amdgcn_mfma_f32_32x32x16_bf16(a, bn, accn, 0, 0, 0);
        }
        __syncthreads();   // everyone done READING h_t

        #pragma unroll
        for (int e = 0; e < 16; ++e) {
            int row = (e & 3) + 8 * (e >> 2) + 4 * kh;
            float yv = y[(size_t)(rb + row) * S_SZ + t];
            float r  = sigmoidf_(gv[0][e] + yv * wy_g[0] + accr[e]);
            float z  = sigmoidf_(gv[1][e] + yv * wy_g[1] + accz[e]);
            float nn = tanhf_(gv[2][e] + yv * wy_g[2] + r * accn[e]);
            float h  = nn + z * (hprev[e] - nn);
            hprev[e] = h;
            hsh[row][hcol] = f2bf(h);
        }
        __syncthreads();   // h_{t+1} visible to all

        // output projection: all 512 threads -> (row, o, k-quarter) partials
        {
            int prow = tid >> 4;
            int po   = (tid >> 2) & 3;
            int pkq  = tid & 3;
            float s = 0.f;
            #pragma unroll
            for (int j = 0; j < 8; ++j) {
                v8s hv = *(const v8s*)&hsh[prow][pkq * 64 + j * 8];
                const float* lw = &lwsh[po][pkq * 64 + j * 8];
                #pragma unroll
                for (int q = 0; q < 8; ++q)
                    s += bf2f((unsigned short)hv[q]) * lw[q];
            }
            psum[prow][po][pkq] = s;
        }
        __syncthreads();   // psum ready (also orders next-iter hsh writes)
        if (tid < 128) {
            int prow = tid >> 2, po = tid & 3;
            v4f p = *(const v4f*)&psum[prow][po][0];
            out[(size_t)(rb + prow) * (S_SZ * 4) + t * 4 + po] =
                p[0] + p[1] + p[2] + p[3] + linb[po];
        }
        // next-iter psum writes happen after two more barriers -> no race
    }
}

// ---------------------------------------------------------------- launch
extern "C" void kernel_launch(void* const* d_in, const int* in_sizes, int n_in,
                              void* d_out, int out_size, void* d_ws, size_t ws_size,
                              hipStream_t stream)
{
    const float* x    = (const float*)d_in[0];
    const float* y    = (const float*)d_in[1];
    const float* eWih = (const float*)d_in[2];
    const float* eWhh = (const float*)d_in[3];
    const float* ebih = (const float*)d_in[4];
    const float* ebhh = (const float*)d_in[5];
    const float* dWih = (const float*)d_in[6];
    const float* dWhh = (const float*)d_in[7];
    const float* dbih = (const float*)d_in[8];
    const float* dbhh = (const float*)d_in[9];
    const float* linW = (const float*)d_in[10];
    const float* linb = (const float*)d_in[11];
    float* out = (float*)d_out;

    char* ws = (char*)d_ws;
    // ws layout (bytes):
    //   wihp     @ 0       : 768*136*2   = 208896
    //   eWhh_bf  @ 208896  : 384*128*2   =  98304   -> 307200
    //   eWih_bf  @ 307200  : 384*5*2     =   3840   -> 311296 (pad to 16B)
    //   dWhh_bf  @ 311296  : 768*256*2   = 393216   -> 704512
    //   ctex     @ 704512  : 4096*128*2  = 1048576  -> 1753088
    //   gib      @ 1753088 : 4096*768*2  = 6291456  -> 8044544
    unsigned short* wihp    = (unsigned short*)(ws);
    unsigned short* eWhh_bf = (unsigned short*)(ws + 208896);
    unsigned short* eWih_bf = (unsigned short*)(ws + 307200);
    unsigned short* dWhh_bf = (unsigned short*)(ws + 311296);
    unsigned short* ctex    = (unsigned short*)(ws + 704512);
    unsigned short* gib     = (unsigned short*)(ws + 1753088);

    prep_kernel<<<2048, 256, 0, stream>>>(dWih, eWhh, eWih, dWhh,
                                          wihp, eWhh_bf, eWih_bf, dWhh_bf, out);
    enc_kernel<<<256, 512, 0, stream>>>(x, eWih_bf, eWhh_bf, ebih, ebhh, ctex);
    gib_kernel<<<dim3(64, 12), 256, 0, stream>>>(ctex, wihp, dbih, gib);
    dec_fused_kernel<<<128, 512, 0, stream>>>(dWhh_bf, dWih, dbhh, y, gib,
                                              linW, linb, out);
}

// Round 6
// 220.305 us; speedup vs baseline: 1.9445x; 1.9445x over previous
//
#include <hip/hip_runtime.h>

#define B_SZ 4096
#define S_SZ 128
#define XD 5
#define EH 128
#define DH 256
#define DSTEPS 10

typedef short v8s __attribute__((ext_vector_type(8)));
typedef float v4f __attribute__((ext_vector_type(4)));

__device__ __forceinline__ float bf2f(unsigned short u) {
    union { unsigned int i; float f; } v; v.i = ((unsigned int)u) << 16; return v.f;
}
__device__ __forceinline__ unsigned short f2bf(float f) {
    union { float f; unsigned int i; } v; v.f = f;
    unsigned int x = v.i;
    return (unsigned short)((x + 0x7FFFu + ((x >> 16) & 1u)) >> 16);
}
__device__ __forceinline__ float fexp2(float x) { return __builtin_amdgcn_exp2f(x); }
__device__ __forceinline__ float frcp(float x) { return __builtin_amdgcn_rcpf(x); }
__device__ __forceinline__ float sigmoidf_(float x) {
    return frcp(1.f + fexp2(-1.44269504088896f * x));
}
__device__ __forceinline__ float tanhf_(float x) {
    float e = fexp2(2.88539008177793f * x);   // e^(2x)
    return 1.f - 2.f * frcp(e + 1.f);
}

// ---------------------------------------------------------------- encoder
// r2 core + absorbed prep: weight frags converted fp32->bf16 in-register;
// side-job writes bf16 dWhh + padded dWih for the decoder (~2.3KB/block).
// Launch-count is the session bottleneck (~10-14us/dispatch): 14 -> 2.
__global__ __launch_bounds__(512) void enc_kernel(
    const float* __restrict__ x,       // [B][S][5] fp32
    const float* __restrict__ Wih32,   // [384][5] fp32
    const float* __restrict__ Whh32,   // [384][128] fp32
    const float* __restrict__ bih,     // [384] fp32
    const float* __restrict__ bhh,     // [384] fp32
    const float* __restrict__ dWih,    // [768][129] fp32
    const float* __restrict__ dWhh,    // [768][256] fp32
    unsigned short* __restrict__ wihp,     // out: [768][136] bf16 (col128=y wt)
    unsigned short* __restrict__ dWhh_bf,  // out: [768][256] bf16
    unsigned short* __restrict__ ctex)     // out: [B][128] bf16
{
    __shared__ unsigned short xs[S_SZ][16][8];     // 32 KB
    __shared__ unsigned short hb[2][16][136];      // 8.5 KB, +8 pad
    __shared__ unsigned short zpad[8];

    const int tid = threadIdx.x;
    const int bid = blockIdx.x;
    const int wv = tid >> 6;
    const int lane = tid & 63;
    const int n = lane & 15;
    const int kg = lane >> 4;       // K-group / C-row quad
    const int r0 = bid * 16;

    // side-job: decoder weight conversion (grid-stride over 131072 threads)
    for (int i = bid * 512 + tid; i < 768 * 256; i += 131072)
        dWhh_bf[i] = f2bf(dWhh[i]);
    for (int i = bid * 512 + tid; i < 768 * 136; i += 131072) {
        int col = i / 136, k = i - col * 136;
        wihp[i] = (k < 129) ? f2bf(dWih[col * 129 + k]) : (unsigned short)0;
    }

    for (int i = tid; i < 2 * 16 * 136; i += 512) ((unsigned short*)hb)[i] = 0;
    if (tid < 8) zpad[tid] = 0;
    for (int i = tid; i < 16 * S_SZ * 8; i += 512) {
        int m = i >> 10;
        int rem = i & 1023;
        int t = rem >> 3;
        int j = rem & 7;
        unsigned short v = 0;
        if (j < XD) v = f2bf(x[(size_t)(r0 + m) * (S_SZ * XD) + t * XD + j]);
        xs[t][m][j] = v;
    }

    const int colw = wv * 16 + n;
    v8s fw[3][4];
    v8s fx[3];
    #pragma unroll
    for (int g = 0; g < 3; ++g) {
        int gcol = g * EH + colw;
        #pragma unroll
        for (int kt = 0; kt < 4; ++kt) {
            const float* p = &Whh32[(size_t)gcol * EH + kt * 32 + kg * 8];
            float4 lo = *(const float4*)p;
            float4 hi = *(const float4*)(p + 4);
            v8s f;
            f[0] = (short)f2bf(lo.x); f[1] = (short)f2bf(lo.y);
            f[2] = (short)f2bf(lo.z); f[3] = (short)f2bf(lo.w);
            f[4] = (short)f2bf(hi.x); f[5] = (short)f2bf(hi.y);
            f[6] = (short)f2bf(hi.z); f[7] = (short)f2bf(hi.w);
            fw[g][kt] = f;
        }
        v8s t = {0, 0, 0, 0, 0, 0, 0, 0};
        if (kg == 0) {
            const float* p = &Wih32[gcol * XD];
            #pragma unroll
            for (int j = 0; j < XD; ++j) t[j] = (short)f2bf(p[j]);
        }
        fx[g] = t;
    }
    const float b_r  = bih[colw]          + bhh[colw];
    const float b_z  = bih[EH + colw]     + bhh[EH + colw];
    const float bi_n = bih[2 * EH + colw];
    const float bh_n = bhh[2 * EH + colw];

    float hst[4] = {0.f, 0.f, 0.f, 0.f};
    __syncthreads();

    #pragma unroll 2
    for (int t = 0; t < S_SZ; ++t) {
        const int p = t & 1;
        v8s a[4];
        #pragma unroll
        for (int kt = 0; kt < 4; ++kt)
            a[kt] = *(const v8s*)&hb[p][n][kt * 32 + kg * 8];
        const unsigned short* xsrc = (kg == 0) ? &xs[t][n][0] : &zpad[0];
        v8s ax = *(const v8s*)xsrc;

        v4f accr  = {b_r, b_r, b_r, b_r};
        v4f accz  = {b_z, b_z, b_z, b_z};
        v4f acchn = {bh_n, bh_n, bh_n, bh_n};
        v4f accin = {bi_n, bi_n, bi_n, bi_n};
        #pragma unroll
        for (int kt = 0; kt < 4; ++kt) {
            accr  = __builtin_amdgcn_mfma_f32_16x16x32_bf16(a[kt], fw[0][kt], accr, 0, 0, 0);
            accz  = __builtin_amdgcn_mfma_f32_16x16x32_bf16(a[kt], fw[1][kt], accz, 0, 0, 0);
            acchn = __builtin_amdgcn_mfma_f32_16x16x32_bf16(a[kt], fw[2][kt], acchn, 0, 0, 0);
        }
        accr  = __builtin_amdgcn_mfma_f32_16x16x32_bf16(ax, fx[0], accr, 0, 0, 0);
        accz  = __builtin_amdgcn_mfma_f32_16x16x32_bf16(ax, fx[1], accz, 0, 0, 0);
        accin = __builtin_amdgcn_mfma_f32_16x16x32_bf16(ax, fx[2], accin, 0, 0, 0);

        #pragma unroll
        for (int e = 0; e < 4; ++e) {
            float r = sigmoidf_(accr[e]);
            float z = sigmoidf_(accz[e]);
            float nn = tanhf_(accin[e] + r * acchn[e]);
            float h = (1.f - z) * nn + z * hst[e];
            hst[e] = h;
            hb[1 - p][kg * 4 + e][colw] = f2bf(h);
        }
        __syncthreads();
    }
    #pragma unroll
    for (int e = 0; e < 4; ++e)
        ctex[(size_t)(r0 + kg * 4 + e) * EH + colw] = f2bf(hst[e]);
}

// ---------------------------------------------------------------- fused decoder
// ONE launch: gi precompute + 10 GRU steps + out-proj + tail pad.
// 256 blocks x 1024 thr (16 waves, 4/SIMD); block = 16 batch rows x ALL 256
// h-cols (recurrence closed per block). Wave w owns hcols [16w,16w+16).
// r/z Whh B-frags resident in VGPRs (64); n-gate Whh in 128KB LDS
// (frag layout: 16-lane-contiguous ds_read_b128, conflict-clean).
// h ping-pongs in an 8KB frag-layout buffer; 2 barriers/step.
// Frag layout: element (row,k) at [((k>>5)*4+((k>>3)&3))*128 + row*8 + (k&7)].
__global__ __launch_bounds__(1024)
__attribute__((amdgpu_waves_per_eu(4, 4)))
void dec_all_kernel(
    const unsigned short* __restrict__ dWhh_bf, // [768][256] bf16
    const unsigned short* __restrict__ wihp,    // [768][136] bf16
    const float* __restrict__ dbih,   // [768]
    const float* __restrict__ dbhh,   // [768]
    const float* __restrict__ y,      // [B][128] fp32
    const unsigned short* __restrict__ ctex,  // [B][128] bf16
    const float* __restrict__ linW,   // [4][256] fp32
    const float* __restrict__ linb,   // [4] fp32
    float* __restrict__ out)          // [B][S][4] fp32
{
    __shared__ unsigned short hshf[32 * 16 * 8];     // 8 KB   h state
    __shared__ unsigned short wshnf[32 * 256 * 8];   // 128 KB n-gate Whh
    __shared__ unsigned short lwf[32 * 16 * 8];      // 8 KB   linW^T (padded to 16)

    const int tid = threadIdx.x;
    const int w = tid >> 6;
    const int lane = tid & 63;
    const int n = lane & 15;
    const int kg = lane >> 4;
    const int rb = blockIdx.x * 16;
    const int hcol = w * 16 + n;

    // stage n-gate Whh into frag layout (once)
    for (int i = tid; i < 8192; i += 1024) {
        int wcol = i >> 5, kc = i & 31;
        uint4 v = *(const uint4*)&dWhh_bf[(size_t)(512 + wcol) * 256 + kc * 8];
        *(uint4*)&wshnf[(kc * 256 + wcol) * 8] = v;
    }
    // stage linW (bf16, padded to 16 cols) into frag layout
    if (tid < 512) {
        int col = tid >> 5, kc = tid & 31;
        unsigned short v8[8];
        #pragma unroll
        for (int j = 0; j < 8; ++j)
            v8[j] = (col < 4) ? f2bf(linW[col * 256 + kc * 8 + j]) : (unsigned short)0;
        *(uint4*)&lwf[(kc * 16 + col) * 8] = *(uint4*)v8;
    }
    // h0 = 1
    for (int i = tid; i < 32 * 16 * 8; i += 1024) hshf[i] = 0x3F80;

    // resident r/z B-frags (64 VGPRs)
    v8s fB[2][8];
    #pragma unroll
    for (int g = 0; g < 2; ++g)
        #pragma unroll
        for (int kt = 0; kt < 8; ++kt)
            fB[g][kt] = *(const v8s*)&dWhh_bf[(size_t)(g * 256 + hcol) * 256 + kt * 32 + kg * 8];

    // gi = ctex @ dWih[:, :128]^T + biases (bhh folded for r,z; not for n)
    const float bR0 = dbih[hcol] + dbhh[hcol];
    const float bZ0 = dbih[DH + hcol] + dbhh[DH + hcol];
    const float bN0 = dbih[2 * DH + hcol];
    const float bN  = dbhh[2 * DH + hcol];
    const float wy0 = bf2f(wihp[(size_t)(0 * DH + hcol) * 136 + 128]);
    const float wy1 = bf2f(wihp[(size_t)(1 * DH + hcol) * 136 + 128]);
    const float wy2 = bf2f(wihp[(size_t)(2 * DH + hcol) * 136 + 128]);

    v4f gvr = {bR0, bR0, bR0, bR0};
    v4f gvz = {bZ0, bZ0, bZ0, bZ0};
    v4f gvn = {bN0, bN0, bN0, bN0};
    #pragma unroll
    for (int kt = 0; kt < 4; ++kt) {
        v8s a  = *(const v8s*)&ctex[(size_t)(rb + n) * EH + kt * 32 + kg * 8];
        v8s b0 = *(const v8s*)&wihp[(size_t)(0 * DH + hcol) * 136 + kt * 32 + kg * 8];
        v8s b1 = *(const v8s*)&wihp[(size_t)(1 * DH + hcol) * 136 + kt * 32 + kg * 8];
        v8s b2 = *(const v8s*)&wihp[(size_t)(2 * DH + hcol) * 136 + kt * 32 + kg * 8];
        gvr = __builtin_amdgcn_mfma_f32_16x16x32_bf16(a, b0, gvr, 0, 0, 0);
        gvz = __builtin_amdgcn_mfma_f32_16x16x32_bf16(a, b1, gvz, 0, 0, 0);
        gvn = __builtin_amdgcn_mfma_f32_16x16x32_bf16(a, b2, gvn, 0, 0, 0);
    }

    const float lb = linb[n & 3];
    // h-write target in frag layout for col=hcol
    const int wfrag = ((w >> 1) * 4 + ((2 * w + (n >> 3)) & 3)) * 128 + (n & 7);

    float hprev[4] = {1.f, 1.f, 1.f, 1.f};
    __syncthreads();

    for (int t = 0; t < DSTEPS; ++t) {
        float yv[4];
        #pragma unroll
        for (int e = 0; e < 4; ++e)
            yv[e] = y[(size_t)(rb + kg * 4 + e) * S_SZ + t];

        v4f accr = {0.f, 0.f, 0.f, 0.f};
        v4f accz = {0.f, 0.f, 0.f, 0.f};
        v4f accn = {bN, bN, bN, bN};
        #pragma unroll
        for (int kt = 0; kt < 8; ++kt) {
            v8s a   = *(const v8s*)&hshf[((kt * 4 + kg) * 16 + n) * 8];
            v8s bn_ = *(const v8s*)&wshnf[((kt * 4 + kg) * 256 + hcol) * 8];
            accr = __builtin_amdgcn_mfma_f32_16x16x32_bf16(a, fB[0][kt], accr, 0, 0, 0);
            accz = __builtin_amdgcn_mfma_f32_16x16x32_bf16(a, fB[1][kt], accz, 0, 0, 0);
            accn = __builtin_amdgcn_mfma_f32_16x16x32_bf16(a, bn_,      accn, 0, 0, 0);
        }
        __syncthreads();   // all waves done READING h_t

        #pragma unroll
        for (int e = 0; e < 4; ++e) {
            float r  = sigmoidf_(gvr[e] + yv[e] * wy0 + accr[e]);
            float z  = sigmoidf_(gvz[e] + yv[e] * wy1 + accz[e]);
            float nn = tanhf_(gvn[e] + yv[e] * wy2 + r * accn[e]);
            float h  = nn + z * (hprev[e] - nn);
            hprev[e] = h;
            hshf[wfrag + (kg * 4 + e) * 8] = f2bf(h);
        }
        __syncthreads();   // h_{t+1} visible

        if (w == 0) {      // out-proj: one wave, one 16x16x32 MFMA chain
            v4f o4 = {0.f, 0.f, 0.f, 0.f};
            #pragma unroll
            for (int kt = 0; kt < 8; ++kt) {
                v8s a = *(const v8s*)&hshf[((kt * 4 + kg) * 16 + n) * 8];
                v8s b = *(const v8s*)&lwf[((kt * 4 + kg) * 16 + n) * 8];
                o4 = __builtin_amdgcn_mfma_f32_16x16x32_bf16(a, b, o4, 0, 0, 0);
            }
            if (n < 4) {
                #pragma unroll
                for (int e = 0; e < 4; ++e)
                    out[(size_t)(rb + kg * 4 + e) * (S_SZ * 4) + t * 4 + n] = o4[e] + lb;
            }
        }
    }

    // tail pad: out[:, 10:, :] = 1.0
    for (int j = tid; j < 16 * 512; j += 1024) {
        int row = j >> 9, c = j & 511;
        if (c >= DSTEPS * 4) out[(size_t)(rb + row) * 512 + c] = 1.0f;
    }
}

// ---------------------------------------------------------------- launch
extern "C" void kernel_launch(void* const* d_in, const int* in_sizes, int n_in,
                              void* d_out, int out_size, void* d_ws, size_t ws_size,
                              hipStream_t stream)
{
    const float* x    = (const float*)d_in[0];
    const float* y    = (const float*)d_in[1];
    const float* eWih = (const float*)d_in[2];
    const float* eWhh = (const float*)d_in[3];
    const float* ebih = (const float*)d_in[4];
    const float* ebhh = (const float*)d_in[5];
    const float* dWih = (const float*)d_in[6];
    const float* dWhh = (const float*)d_in[7];
    const float* dbih = (const float*)d_in[8];
    const float* dbhh = (const float*)d_in[9];
    const float* linW = (const float*)d_in[10];
    const float* linb = (const float*)d_in[11];
    float* out = (float*)d_out;

    char* ws = (char*)d_ws;
    // ws layout (bytes):
    //   wihp     @ 0      : 768*136*2 = 208896
    //   dWhh_bf  @ 208896 : 768*256*2 = 393216  -> 602112
    //   ctex     @ 602112 : 4096*128*2 = 1048576 -> 1650688
    unsigned short* wihp    = (unsigned short*)(ws);
    unsigned short* dWhh_bf = (unsigned short*)(ws + 208896);
    unsigned short* ctex    = (unsigned short*)(ws + 602112);

    enc_kernel<<<256, 512, 0, stream>>>(x, eWih, eWhh, ebih, ebhh,
                                        dWih, dWhh, wihp, dWhh_bf, ctex);
    dec_all_kernel<<<256, 1024, 0, stream>>>(dWhh_bf, wihp, dbih, dbhh, y,
                                             ctex, linW, linb, out);
}

// Round 7
// 217.420 us; speedup vs baseline: 1.9704x; 1.0133x over previous
//
#include <hip/hip_runtime.h>

#define B_SZ 4096
#define S_SZ 128
#define XD 5
#define EH 128
#define DH 256
#define DSTEPS 10

typedef short v8s __attribute__((ext_vector_type(8)));
typedef float v4f __attribute__((ext_vector_type(4)));

__device__ __forceinline__ float bf2f(unsigned short u) {
    union { unsigned int i; float f; } v; v.i = ((unsigned int)u) << 16; return v.f;
}
__device__ __forceinline__ unsigned short f2bf(float f) {
    union { float f; unsigned int i; } v; v.f = f;
    unsigned int x = v.i;
    return (unsigned short)((x + 0x7FFFu + ((x >> 16) & 1u)) >> 16);
}
__device__ __forceinline__ float fexp2(float x) { return __builtin_amdgcn_exp2f(x); }
__device__ __forceinline__ float frcp(float x) { return __builtin_amdgcn_rcpf(x); }
__device__ __forceinline__ float sigmoidf_(float x) {
    return frcp(1.f + fexp2(-1.44269504088896f * x));
}
__device__ __forceinline__ float tanhf_(float x) {
    float e = fexp2(2.88539008177793f * x);   // e^(2x)
    return 1.f - 2.f * frcp(e + 1.f);
}

// ---------------------------------------------------------------- encoder
// (unchanged from r6: r2 core + absorbed weight-prep side-job)
__global__ __launch_bounds__(512) void enc_kernel(
    const float* __restrict__ x,       // [B][S][5] fp32
    const float* __restrict__ Wih32,   // [384][5] fp32
    const float* __restrict__ Whh32,   // [384][128] fp32
    const float* __restrict__ bih,     // [384] fp32
    const float* __restrict__ bhh,     // [384] fp32
    const float* __restrict__ dWih,    // [768][129] fp32
    const float* __restrict__ dWhh,    // [768][256] fp32
    unsigned short* __restrict__ wihp,     // out: [768][136] bf16 (col128=y wt)
    unsigned short* __restrict__ dWhh_bf,  // out: [768][256] bf16
    unsigned short* __restrict__ ctex)     // out: [B][128] bf16
{
    __shared__ unsigned short xs[S_SZ][16][8];     // 32 KB
    __shared__ unsigned short hb[2][16][136];      // 8.5 KB, +8 pad
    __shared__ unsigned short zpad[8];

    const int tid = threadIdx.x;
    const int bid = blockIdx.x;
    const int wv = tid >> 6;
    const int lane = tid & 63;
    const int n = lane & 15;
    const int kg = lane >> 4;       // K-group / C-row quad
    const int r0 = bid * 16;

    // side-job: decoder weight conversion (grid-stride over 131072 threads)
    for (int i = bid * 512 + tid; i < 768 * 256; i += 131072)
        dWhh_bf[i] = f2bf(dWhh[i]);
    for (int i = bid * 512 + tid; i < 768 * 136; i += 131072) {
        int col = i / 136, k = i - col * 136;
        wihp[i] = (k < 129) ? f2bf(dWih[col * 129 + k]) : (unsigned short)0;
    }

    for (int i = tid; i < 2 * 16 * 136; i += 512) ((unsigned short*)hb)[i] = 0;
    if (tid < 8) zpad[tid] = 0;
    for (int i = tid; i < 16 * S_SZ * 8; i += 512) {
        int m = i >> 10;
        int rem = i & 1023;
        int t = rem >> 3;
        int j = rem & 7;
        unsigned short v = 0;
        if (j < XD) v = f2bf(x[(size_t)(r0 + m) * (S_SZ * XD) + t * XD + j]);
        xs[t][m][j] = v;
    }

    const int colw = wv * 16 + n;
    v8s fw[3][4];
    v8s fx[3];
    #pragma unroll
    for (int g = 0; g < 3; ++g) {
        int gcol = g * EH + colw;
        #pragma unroll
        for (int kt = 0; kt < 4; ++kt) {
            const float* p = &Whh32[(size_t)gcol * EH + kt * 32 + kg * 8];
            float4 lo = *(const float4*)p;
            float4 hi = *(const float4*)(p + 4);
            v8s f;
            f[0] = (short)f2bf(lo.x); f[1] = (short)f2bf(lo.y);
            f[2] = (short)f2bf(lo.z); f[3] = (short)f2bf(lo.w);
            f[4] = (short)f2bf(hi.x); f[5] = (short)f2bf(hi.y);
            f[6] = (short)f2bf(hi.z); f[7] = (short)f2bf(hi.w);
            fw[g][kt] = f;
        }
        v8s t = {0, 0, 0, 0, 0, 0, 0, 0};
        if (kg == 0) {
            const float* p = &Wih32[gcol * XD];
            #pragma unroll
            for (int j = 0; j < XD; ++j) t[j] = (short)f2bf(p[j]);
        }
        fx[g] = t;
    }
    const float b_r  = bih[colw]          + bhh[colw];
    const float b_z  = bih[EH + colw]     + bhh[EH + colw];
    const float bi_n = bih[2 * EH + colw];
    const float bh_n = bhh[2 * EH + colw];

    float hst[4] = {0.f, 0.f, 0.f, 0.f};
    __syncthreads();

    #pragma unroll 2
    for (int t = 0; t < S_SZ; ++t) {
        const int p = t & 1;
        v8s a[4];
        #pragma unroll
        for (int kt = 0; kt < 4; ++kt)
            a[kt] = *(const v8s*)&hb[p][n][kt * 32 + kg * 8];
        const unsigned short* xsrc = (kg == 0) ? &xs[t][n][0] : &zpad[0];
        v8s ax = *(const v8s*)xsrc;

        v4f accr  = {b_r, b_r, b_r, b_r};
        v4f accz  = {b_z, b_z, b_z, b_z};
        v4f acchn = {bh_n, bh_n, bh_n, bh_n};
        v4f accin = {bi_n, bi_n, bi_n, bi_n};
        #pragma unroll
        for (int kt = 0; kt < 4; ++kt) {
            accr  = __builtin_amdgcn_mfma_f32_16x16x32_bf16(a[kt], fw[0][kt], accr, 0, 0, 0);
            accz  = __builtin_amdgcn_mfma_f32_16x16x32_bf16(a[kt], fw[1][kt], accz, 0, 0, 0);
            acchn = __builtin_amdgcn_mfma_f32_16x16x32_bf16(a[kt], fw[2][kt], acchn, 0, 0, 0);
        }
        accr  = __builtin_amdgcn_mfma_f32_16x16x32_bf16(ax, fx[0], accr, 0, 0, 0);
        accz  = __builtin_amdgcn_mfma_f32_16x16x32_bf16(ax, fx[1], accz, 0, 0, 0);
        accin = __builtin_amdgcn_mfma_f32_16x16x32_bf16(ax, fx[2], accin, 0, 0, 0);

        #pragma unroll
        for (int e = 0; e < 4; ++e) {
            float r = sigmoidf_(accr[e]);
            float z = sigmoidf_(accz[e]);
            float nn = tanhf_(accin[e] + r * acchn[e]);
            float h = (1.f - z) * nn + z * hst[e];
            hst[e] = h;
            hb[1 - p][kg * 4 + e][colw] = f2bf(h);
        }
        __syncthreads();
    }
    #pragma unroll
    for (int e = 0; e < 4; ++e)
        ctex[(size_t)(r0 + kg * 4 + e) * EH + colw] = f2bf(hst[e]);
}

// ---------------------------------------------------------------- fused decoder v2
// 256 blocks x 512 thr (8 waves = 2/EU -> 256-VGPR budget; r6's 1024-thr
// block capped VGPR at 128 and spilled/refetched the resident frags).
// Block = 16 rows x all 256 h-cols. Wave w owns h-cols [32w,32w+32) as two
// 16-col groups. r/z Whh: 128 VGPRs resident. n-gate Whh: 132 KB LDS in
// frag layout (+8 col pad). h: 8 KB frag-layout LDS. 2 barriers/step.
// Frag layout: element (m,k) at [((k>>3)*M + m)*8 + (k&7)].
__global__ __launch_bounds__(512)
__attribute__((amdgpu_waves_per_eu(2, 2)))
void dec_all_kernel(
    const unsigned short* __restrict__ dWhh_bf, // [768][256] bf16
    const unsigned short* __restrict__ wihp,    // [768][136] bf16
    const float* __restrict__ dbih,   // [768]
    const float* __restrict__ dbhh,   // [768]
    const float* __restrict__ y,      // [B][128] fp32
    const unsigned short* __restrict__ ctex,  // [B][128] bf16
    const float* __restrict__ linW,   // [4][256] fp32
    const float* __restrict__ linb,   // [4] fp32
    float* __restrict__ out)          // [B][S][4] fp32
{
    __shared__ unsigned short wshn[32 * 264 * 8];  // 132 KB n-gate Whh (frag, pad 264)
    __shared__ unsigned short hshf[32 * 16 * 8];   // 8 KB   h state (frag)
    __shared__ unsigned short lwf[32 * 16 * 8];    // 8 KB   linW (frag, 4->16 pad)

    const int tid  = threadIdx.x;
    const int w    = tid >> 6;
    const int lane = tid & 63;
    const int n    = lane & 15;
    const int kg   = lane >> 4;
    const int rb   = blockIdx.x * 16;
    const int cbase = w * 32;

    // stage n-gate Whh (once; coalesced global reads)
    for (int i = tid; i < 256 * 32; i += 512) {
        int col = i >> 5, kgrp = i & 31;
        uint4 v = *(const uint4*)&dWhh_bf[(size_t)(512 + col) * 256 + kgrp * 8];
        *(uint4*)&wshn[(kgrp * 264 + col) * 8] = v;
    }
    // stage linW into frag layout
    {
        int col = tid >> 5, kgrp = tid & 31;
        unsigned short v8[8];
        #pragma unroll
        for (int j = 0; j < 8; ++j)
            v8[j] = (col < 4) ? f2bf(linW[col * 256 + kgrp * 8 + j]) : (unsigned short)0;
        *(uint4*)&lwf[(kgrp * 16 + col) * 8] = *(uint4*)v8;
    }
    // h0 = 1
    for (int i = tid; i < 32 * 16 * 8; i += 512) hshf[i] = 0x3F80;

    // resident r/z B-frags: 2 gates x 2 colgroups x 8 K-tiles = 128 VGPRs
    v8s fB[2][2][8];
    #pragma unroll
    for (int g = 0; g < 2; ++g)
        #pragma unroll
        for (int cg = 0; cg < 2; ++cg)
            #pragma unroll
            for (int kt = 0; kt < 8; ++kt)
                fB[g][cg][kt] = *(const v8s*)
                    &dWhh_bf[(size_t)(g * DH + cbase + cg * 16 + n) * DH + kt * 32 + kg * 8];

    // gi = ctex @ dWih[:, :128]^T + dbih (+dbhh for r,z); y weight per col
    v4f gi[3][2];
    float wy[3][2], bNh[2];
    #pragma unroll
    for (int g = 0; g < 3; ++g)
        #pragma unroll
        for (int cg = 0; cg < 2; ++cg) {
            int gcol = g * DH + cbase + cg * 16 + n;
            float bb = dbih[gcol] + ((g < 2) ? dbhh[gcol] : 0.f);
            gi[g][cg] = (v4f){bb, bb, bb, bb};
            wy[g][cg] = bf2f(wihp[(size_t)gcol * 136 + 128]);
        }
    #pragma unroll
    for (int cg = 0; cg < 2; ++cg)
        bNh[cg] = dbhh[2 * DH + cbase + cg * 16 + n];

    #pragma unroll
    for (int kt = 0; kt < 4; ++kt) {
        v8s a = *(const v8s*)&ctex[(size_t)(rb + n) * EH + kt * 32 + kg * 8];
        #pragma unroll
        for (int g = 0; g < 3; ++g)
            #pragma unroll
            for (int cg = 0; cg < 2; ++cg) {
                v8s b = *(const v8s*)
                    &wihp[(size_t)(g * DH + cbase + cg * 16 + n) * 136 + kt * 32 + kg * 8];
                gi[g][cg] = __builtin_amdgcn_mfma_f32_16x16x32_bf16(a, b, gi[g][cg], 0, 0, 0);
            }
    }

    const float lb = (n < 4) ? linb[n] : 0.f;
    float hprev[2][4];
    #pragma unroll
    for (int cg = 0; cg < 2; ++cg)
        #pragma unroll
        for (int e = 0; e < 4; ++e) hprev[cg][e] = 1.0f;

    __syncthreads();

    for (int t = 0; t < DSTEPS; ++t) {
        float yv[4];
        #pragma unroll
        for (int e = 0; e < 4; ++e)
            yv[e] = y[(size_t)(rb + kg * 4 + e) * S_SZ + t];

        v4f ar[2], az[2], an[2];
        #pragma unroll
        for (int cg = 0; cg < 2; ++cg) {
            ar[cg] = (v4f){0.f, 0.f, 0.f, 0.f};
            az[cg] = (v4f){0.f, 0.f, 0.f, 0.f};
            an[cg] = (v4f){bNh[cg], bNh[cg], bNh[cg], bNh[cg]};
        }
        #pragma unroll
        for (int kt = 0; kt < 8; ++kt) {
            v8s a = *(const v8s*)&hshf[((kt * 4 + kg) * 16 + n) * 8];
            #pragma unroll
            for (int cg = 0; cg < 2; ++cg) {
                v8s bn_ = *(const v8s*)&wshn[((kt * 4 + kg) * 264 + cbase + cg * 16 + n) * 8];
                ar[cg] = __builtin_amdgcn_mfma_f32_16x16x32_bf16(a, fB[0][cg][kt], ar[cg], 0, 0, 0);
                az[cg] = __builtin_amdgcn_mfma_f32_16x16x32_bf16(a, fB[1][cg][kt], az[cg], 0, 0, 0);
                an[cg] = __builtin_amdgcn_mfma_f32_16x16x32_bf16(a, bn_,           an[cg], 0, 0, 0);
            }
        }
        __syncthreads();   // all reads of h_t complete

        #pragma unroll
        for (int cg = 0; cg < 2; ++cg) {
            const int chi = 4 * w + 2 * cg + (n >> 3);   // (col>>3)
            #pragma unroll
            for (int e = 0; e < 4; ++e) {
                float r  = sigmoidf_(gi[0][cg][e] + yv[e] * wy[0][cg] + ar[cg][e]);
                float z  = sigmoidf_(gi[1][cg][e] + yv[e] * wy[1][cg] + az[cg][e]);
                float nn = tanhf_(gi[2][cg][e] + yv[e] * wy[2][cg] + r * an[cg][e]);
                float h  = nn + z * (hprev[cg][e] - nn);
                hprev[cg][e] = h;
                hshf[(chi * 16 + kg * 4 + e) * 8 + (n & 7)] = f2bf(h);
            }
        }
        __syncthreads();   // h_{t+1} visible

        if (w == 0) {      // out-proj (overlaps other waves' next MFMA phase)
            v4f o4 = {0.f, 0.f, 0.f, 0.f};
            #pragma unroll
            for (int kt = 0; kt < 8; ++kt) {
                v8s a = *(const v8s*)&hshf[((kt * 4 + kg) * 16 + n) * 8];
                v8s b = *(const v8s*)&lwf[((kt * 4 + kg) * 16 + n) * 8];
                o4 = __builtin_amdgcn_mfma_f32_16x16x32_bf16(a, b, o4, 0, 0, 0);
            }
            if (n < 4) {
                #pragma unroll
                for (int e = 0; e < 4; ++e)
                    out[(size_t)(rb + kg * 4 + e) * (S_SZ * 4) + t * 4 + n] = o4[e] + lb;
            }
        }
    }

    // tail pad: out[:, 10:, :] = 1.0
    for (int j = tid; j < 16 * 512; j += 512) {
        int row = j >> 9, c = j & 511;
        if (c >= DSTEPS * 4) out[(size_t)(rb + row) * 512 + c] = 1.0f;
    }
}

// ---------------------------------------------------------------- launch
extern "C" void kernel_launch(void* const* d_in, const int* in_sizes, int n_in,
                              void* d_out, int out_size, void* d_ws, size_t ws_size,
                              hipStream_t stream)
{
    const float* x    = (const float*)d_in[0];
    const float* y    = (const float*)d_in[1];
    const float* eWih = (const float*)d_in[2];
    const float* eWhh = (const float*)d_in[3];
    const float* ebih = (const float*)d_in[4];
    const float* ebhh = (const float*)d_in[5];
    const float* dWih = (const float*)d_in[6];
    const float* dWhh = (const float*)d_in[7];
    const float* dbih = (const float*)d_in[8];
    const float* dbhh = (const float*)d_in[9];
    const float* linW = (const float*)d_in[10];
    const float* linb = (const float*)d_in[11];
    float* out = (float*)d_out;

    char* ws = (char*)d_ws;
    // ws layout (bytes):
    //   wihp     @ 0      : 768*136*2 = 208896
    //   dWhh_bf  @ 208896 : 768*256*2 = 393216  -> 602112
    //   ctex     @ 602112 : 4096*128*2 = 1048576 -> 1650688
    unsigned short* wihp    = (unsigned short*)(ws);
    unsigned short* dWhh_bf = (unsigned short*)(ws + 208896);
    unsigned short* ctex    = (unsigned short*)(ws + 602112);

    enc_kernel<<<256, 512, 0, stream>>>(x, eWih, eWhh, ebih, ebhh,
                                        dWih, dWhh, wihp, dWhh_bf, ctex);
    dec_all_kernel<<<256, 512, 0, stream>>>(dWhh_bf, wihp, dbih, dbhh, y,
                                            ctex, linW, linb, out);
}